// Round 10
// baseline (595.124 us; speedup 1.0000x reference)
//
#include <hip/hip_runtime.h>

// DGM forward, MI355X. bf16 MFMA 16x16x32, fp32 accum, fp32 tanh.
// R15: the R8 move, applied again. R8 (halve tile 64->32 cols, double waves)
//      was the only big win (511->366); R9-R14 proved everything else flat.
//      Now: wave tile 32x16, 16 waves (1024 thr), wave w owns cols
//      [w*16,w*16+16). acc[2]=8 AGPR, state arrays 4 regs each; tx[8] hoist
//      deleted (zero reuse at 1 col-block -> acc-init reads txS directly,
//      -16 live regs). Est live set 55-64. __launch_bounds__(1024,8) demands
//      64 regs/wave -> if fit: 2 WGs x 16 waves = 32 waves/CU = 100% occ
//      (2x R8's latency hiding, cross-WG overlap kept). LDS 2x33KB fits.
//      Schedule/math = R8 verbatim otherwise (4 barriers, cvtpk, setprio).
//      pack_w = R14's LDS-transpose (verified).
//
// MFMA 16x16x32 layouts (ln = lane, q = ln>>4, c15 = ln&15):
//  A-frag: lane holds A[m=c15][k=kb*32+q*8+i], i=0..7
//  B-frag: lane holds B[k=kb*32+q*8+i][n=cblk*16+c15]
//  C/D:    lane holds C[row=q*4+ii][col=c15]
// W packed (d_ws) B-frag order per matrix: idx = (((cblk*8+kb)*64+ln)*8+i)
//  (cblk = global 16-col block 0..15; here cblk = w, w=0..15)
// LDS state swizzle: elem(r,k) -> r*256 + (((k>>3)^r)&31)*8 + (k&7)

typedef __attribute__((ext_vector_type(8))) short bf16x8;
typedef __attribute__((ext_vector_type(4))) float f32x4;

#if __has_builtin(__builtin_amdgcn_exp2f)
#define EXP2F(x) __builtin_amdgcn_exp2f(x)
#else
#define EXP2F(x) __expf((x) * 0.6931471805599453f)
#endif

__device__ __forceinline__ short f2bf(float f) {
    unsigned u = __float_as_uint(f);
    unsigned r = (u + 0x7FFFu + ((u >> 16) & 1u)) >> 16;
    return (short)r;
}
__device__ __forceinline__ float bf2f(short h) {
    return __uint_as_float(((unsigned)(unsigned short)h) << 16);
}
// packed bf16 pair via HW convert (RNE, same rounding as f2bf)
__device__ __forceinline__ unsigned cvtpk(float lo, float hi) {
    unsigned r;
    asm("v_cvt_pk_bf16_f32 %0, %1, %2" : "=v"(r) : "v"(lo), "v"(hi));
    return r;
}
// rcp(1 + e^{2x}); tanh(x) = 1 - 2*this; 1 - tanh(x) = 2*this
__device__ __forceinline__ float rcp_1pe2x(float x) {
    float e = EXP2F(x * 2.8853900817779268f);   // 2*log2(e)
    return __builtin_amdgcn_rcpf(e + 1.0f);
}
__device__ __forceinline__ float fast_tanh(float x) {
    return fmaf(-2.0f, rcp_1pe2x(x), 1.0f);
}
__device__ __forceinline__ int sw_off(int r, int k) {
    return r * 256 + ((((k >> 3) ^ r) & 31) << 3) + (k & 7);
}
__device__ __forceinline__ unsigned pk2(float a, float b) { return cvtpk(a, b); }
__device__ __forceinline__ float upk(unsigned p, int hi) {
    return __uint_as_float(hi ? (p & 0xFFFF0000u) : (p << 16));
}

// ---------------- pack weights fp32 -> bf16, B-frag order (LDS transpose) ----------------
__global__ void pack_w(const float* __restrict__ Wz, const float* __restrict__ Wg,
                       const float* __restrict__ Wr, const float* __restrict__ Wh,
                       short* __restrict__ out) {
    __shared__ __align__(16) short lds[256 * 40];   // 20 KB
    int mat = blockIdx.x >> 3;       // 0..11 = l*4+g
    int kb  = blockIdx.x & 7;        // 0..7
    int l = mat >> 2, g = mat & 3;
    const float* W = (g == 0) ? Wz : (g == 1) ? Wg : (g == 2) ? Wr : Wh;
    const float* Wsl = W + l * 65536 + kb * 32 * 256;   // slab [32][256]
    const int t = threadIdx.x;

#pragma unroll
    for (int j = 0; j < 8; j++) {
        int f  = j * 256 + t;
        int kp = f >> 6;
        int n0 = (f & 63) * 4;
        float4 v = ((const float4*)Wsl)[f];
        lds[(n0 + 0) * 40 + kp] = f2bf(v.x);
        lds[(n0 + 1) * 40 + kp] = f2bf(v.y);
        lds[(n0 + 2) * 40 + kp] = f2bf(v.z);
        lds[(n0 + 3) * 40 + kp] = f2bf(v.w);
    }
    __syncthreads();

    short* outm = out + mat * 65536;
#pragma unroll
    for (int j = 0; j < 4; j++) {
        int vp = j * 256 + t;
        int c  = vp >> 6;
        int ln = vp & 63;
        int n   = c * 16 + (ln & 15);
        int kp0 = (ln >> 4) * 8;
        bf16x8 val = *(const bf16x8*)(lds + n * 40 + kp0);
        *(bf16x8*)(outm + (((c * 8 + kb) * 64 + ln) << 3)) = val;
    }
}

// ---------------- one gate GEMM: acc = bias + X@U + In@W ----------------
// wave tile: 32 rows x 16 cols -> acc[2]; cblk = w
__device__ __forceinline__ void gate_gemm(const short* __restrict__ In,   // LDS [32][256] swizzled
                                          const short* __restrict__ Wm,   // packed bf16 65536
                                          const float* __restrict__ U,    // [2][256] fp32
                                          const float* __restrict__ bias, // [256]
                                          const float2* __restrict__ txS, // LDS [32]
                                          int q, int c15, int w,
                                          f32x4 acc[2]) {
    int col = w * 16 + c15;
    float u0 = U[col], u1 = U[256 + col], bb = bias[col];
#pragma unroll
    for (int rb = 0; rb < 2; rb++)
#pragma unroll
        for (int ii = 0; ii < 4; ii++) {
            float2 t2 = txS[rb * 16 + q * 4 + ii];   // broadcast read, no hoist
            acc[rb][ii] = bb + t2.x * u0 + t2.y * u1;
        }
    __builtin_amdgcn_s_setprio(1);
#pragma unroll
    for (int kb = 0; kb < 8; kb++) {
        bf16x8 a[2];
#pragma unroll
        for (int rb = 0; rb < 2; rb++) {
            int r = rb * 16 + c15;
            a[rb] = *(const bf16x8*)(In + r * 256 + ((((kb * 4 + q) ^ r) & 31) << 3));
        }
        bf16x8 b = *(const bf16x8*)(Wm + (((w * 8 + kb) * 64 + (q * 16 + c15)) << 3));
#pragma unroll
        for (int rb = 0; rb < 2; rb++)
            acc[rb] = __builtin_amdgcn_mfma_f32_16x16x32_bf16(a[rb], b, acc[rb], 0, 0, 0);
    }
    __builtin_amdgcn_s_setprio(0);
}

// ---------------- main kernel: 32 rows/WG, 1024 threads (16 waves) ----------------
__global__ __launch_bounds__(1024, 8)
void dgm_main(const float* __restrict__ T, const float* __restrict__ X,
              const float* __restrict__ W0, const float* __restrict__ b0,
              const float* __restrict__ Uz, const float* __restrict__ Ug,
              const float* __restrict__ Ur, const float* __restrict__ Uh,
              const float* __restrict__ bz, const float* __restrict__ bg,
              const float* __restrict__ br, const float* __restrict__ bh,
              const float* __restrict__ Wf, const float* __restrict__ bfp,
              const short* __restrict__ Wp, float* __restrict__ out) {
    __shared__ __align__(16) short Sb[8192];    // 16 KB: S (holds S*R mid-layer)
    __shared__ __align__(16) short S1b[8192];   // 16 KB: S1, immutable
    __shared__ float2 txS[32];

    const int tid = threadIdx.x;
    const int w   = tid >> 6;        // 0..15
    const int ln  = tid & 63;
    const int q   = ln >> 4;
    const int c15 = ln & 15;
    const int m0  = blockIdx.x * 32;

    if (tid < 32) txS[tid] = make_float2(T[m0 + tid], X[m0 + tid]);
    __syncthreads();

    // ---- S1 = tanh(X@W0 + b0); S = S1. 1024 thr: (col, quarter of rows) ----
    {
        int col = tid & 255;
        int qt  = tid >> 8;          // 0..3 -> rows [qt*8, qt*8+8)
        float w00 = W0[col], w01 = W0[256 + col], bb = b0[col];
#pragma unroll
        for (int rr = 0; rr < 8; rr++) {
            int r = qt * 8 + rr;
            float2 tx = txS[r];
            short v = f2bf(fast_tanh(tx.x * w00 + tx.y * w01 + bb));
            int off = sw_off(r, col);
            S1b[off] = v;
            Sb[off]  = v;
        }
    }
    __syncthreads();

    const int colw = w * 16 + c15;   // this thread's owned column

    // register mirror of this thread's owned S elements (C-layout), packed bf16
    unsigned sreg[2][2];
#pragma unroll
    for (int rb = 0; rb < 2; rb++)
#pragma unroll
        for (int p = 0; p < 2; p++) {
            unsigned lo = (unsigned short)Sb[sw_off(rb * 16 + q * 4 + 2 * p,     colw)];
            unsigned hi = (unsigned short)Sb[sw_off(rb * 16 + q * 4 + 2 * p + 1, colw)];
            sreg[rb][p] = lo | (hi << 16);
        }

    // ---- layers ----
    for (int l = 0; l < 3; l++) {
        const short* Wzp = Wp + (l * 4 + 0) * 65536;
        const short* Wgp = Wp + (l * 4 + 1) * 65536;
        const short* Wrp = Wp + (l * 4 + 2) * 65536;
        const short* Whp = Wp + (l * 4 + 3) * 65536;

        f32x4 acc[2];
        unsigned zsp[2][2], srp[2][2], gmp[2][2];

        // Z gate: zs = tanh(Z)*S_old
        gate_gemm(Sb, Wzp, Uz + l * 512, bz + l * 256, txS, q, c15, w, acc);
#pragma unroll
        for (int rb = 0; rb < 2; rb++)
#pragma unroll
            for (int p = 0; p < 2; p++)
                zsp[rb][p] = pk2(
                    fast_tanh(acc[rb][2 * p])     * upk(sreg[rb][p], 0),
                    fast_tanh(acc[rb][2 * p + 1]) * upk(sreg[rb][p], 1));

        // R gate: sr = S_old*tanh(R)
        gate_gemm(Sb, Wrp, Ur + l * 512, br + l * 256, txS, q, c15, w, acc);
#pragma unroll
        for (int rb = 0; rb < 2; rb++)
#pragma unroll
            for (int p = 0; p < 2; p++)
                srp[rb][p] = pk2(
                    upk(sreg[rb][p], 0) * fast_tanh(acc[rb][2 * p]),
                    upk(sreg[rb][p], 1) * fast_tanh(acc[rb][2 * p + 1]));

        // G gate (reads only S1b): 1 - tanh(G) = 2*rcp(e^{2G}+1)
        gate_gemm(S1b, Wgp, Ug + l * 512, bg + l * 256, txS, q, c15, w, acc);
#pragma unroll
        for (int rb = 0; rb < 2; rb++)
#pragma unroll
            for (int p = 0; p < 2; p++)
                gmp[rb][p] = pk2(2.0f * rcp_1pe2x(acc[rb][2 * p]),
                                 2.0f * rcp_1pe2x(acc[rb][2 * p + 1]));

        __syncthreads();   // B1: all Sb reads (Z,R A-frags) done
#pragma unroll
        for (int rb = 0; rb < 2; rb++)
#pragma unroll
            for (int p = 0; p < 2; p++) {
                Sb[sw_off(rb * 16 + q * 4 + 2 * p,     colw)] = (short)(srp[rb][p] & 0xFFFFu);
                Sb[sw_off(rb * 16 + q * 4 + 2 * p + 1, colw)] = (short)(srp[rb][p] >> 16);
            }
        __syncthreads();   // B2: Sb = S*R visible

        // H gate (reads Sb = S*R)
        gate_gemm(Sb, Whp, Uh + l * 512, bh + l * 256, txS, q, c15, w, acc);

        // S_new = (1-G)*tanh(H) + zs  (no Sb access here)
#pragma unroll
        for (int rb = 0; rb < 2; rb++)
#pragma unroll
            for (int p = 0; p < 2; p++) {
                float sn0 = fmaf(upk(gmp[rb][p], 0),
                                 fast_tanh(acc[rb][2 * p]),
                                 upk(zsp[rb][p], 0));
                float sn1 = fmaf(upk(gmp[rb][p], 1),
                                 fast_tanh(acc[rb][2 * p + 1]),
                                 upk(zsp[rb][p], 1));
                srp[rb][p] = pk2(sn0, sn1);
            }

        __syncthreads();   // B3: all H A-frag reads of Sb done
#pragma unroll
        for (int rb = 0; rb < 2; rb++)
#pragma unroll
            for (int p = 0; p < 2; p++) {
                Sb[sw_off(rb * 16 + q * 4 + 2 * p,     colw)] = (short)(srp[rb][p] & 0xFFFFu);
                Sb[sw_off(rb * 16 + q * 4 + 2 * p + 1, colw)] = (short)(srp[rb][p] >> 16);
                sreg[rb][p] = srp[rb][p];
            }
        __syncthreads();   // B4: new S visible
    }

    // ---- out = S @ Wf + bf : 32 threads/row, vectorized LDS reads ----
    {
        int row = tid >> 5;          // 0..31
        int seg = tid & 31;          // 32 threads per row, 1 chunk of 8 each
        bf16x8 sv = *(const bf16x8*)(Sb + row * 256 + (((seg ^ row) & 31) << 3));
        float4 wa = *(const float4*)(Wf + seg * 8);
        float4 wb = *(const float4*)(Wf + seg * 8 + 4);
        float sum = bf2f(sv[0]) * wa.x + bf2f(sv[1]) * wa.y + bf2f(sv[2]) * wa.z + bf2f(sv[3]) * wa.w
                  + bf2f(sv[4]) * wb.x + bf2f(sv[5]) * wb.y + bf2f(sv[6]) * wb.z + bf2f(sv[7]) * wb.w;
        sum += __shfl_down(sum, 16, 32);
        sum += __shfl_down(sum, 8, 32);
        sum += __shfl_down(sum, 4, 32);
        sum += __shfl_down(sum, 2, 32);
        sum += __shfl_down(sum, 1, 32);
        if (seg == 0) out[m0 + row] = sum + bfp[0];
    }
}

extern "C" void kernel_launch(void* const* d_in, const int* in_sizes, int n_in,
                              void* d_out, int out_size, void* d_ws, size_t ws_size,
                              hipStream_t stream) {
    const float* T  = (const float*)d_in[0];
    const float* X  = (const float*)d_in[1];
    const float* W0 = (const float*)d_in[2];
    const float* b0 = (const float*)d_in[3];
    const float* Uz = (const float*)d_in[4];
    const float* Ug = (const float*)d_in[5];
    const float* Ur = (const float*)d_in[6];
    const float* Uh = (const float*)d_in[7];
    const float* Wz = (const float*)d_in[8];
    const float* Wg = (const float*)d_in[9];
    const float* Wr = (const float*)d_in[10];
    const float* Wh = (const float*)d_in[11];
    const float* bz = (const float*)d_in[12];
    const float* bg = (const float*)d_in[13];
    const float* br = (const float*)d_in[14];
    const float* bh = (const float*)d_in[15];
    const float* Wf = (const float*)d_in[16];
    const float* bfp= (const float*)d_in[17];
    float* out = (float*)d_out;
    short* Wp = (short*)d_ws;           // 12*65536 bf16 = 1.5 MB
    const int N = in_sizes[0];

    pack_w<<<96, 256, 0, stream>>>(Wz, Wg, Wr, Wh, Wp);
    dgm_main<<<N / 32, 1024, 0, stream>>>(T, X, W0, b0, Uz, Ug, Ur, Uh,
                                          bz, bg, br, bh, Wf, bfp, Wp, out);
}

// Round 11
// 414.547 us; speedup vs baseline: 1.4356x; 1.4356x over previous
//
#include <hip/hip_runtime.h>

// DGM forward, MI355X. bf16 MFMA 16x16x32, fp32 accum, fp32 tanh.
// R16 = R14 verbatim — restoring the session's verified best after R15's
//      register-spill probe (FETCH/WRITE ~788 MB scratch, 558 us).
//      Closure argument (measured): >=32 waves/CU needs <=64 regs -> spill
//      (R15, R9); M=16-row retile fits regs but doubles L2 weight traffic to
//      the ~34 TB/s L2 ceiling (no net gain); 1x16-wave WG loses cross-WG
//      barrier overlap. VALU cuts (R10/R11, -11pts) and conflict elimination
//      (R11, -3.15M) were time-neutral; dep-break (R12) spilled; barrier
//      restructure (R6) regressed. R8's 2WG x 8wave x 32x32-tile @128regs is
//      the empirical optimum of this structure.
//      dgm_main = R8 VERBATIM; pack_w = LDS-transpose (verified R14).
//
// MFMA 16x16x32 layouts (ln = lane, q = ln>>4, c15 = ln&15):
//  A-frag: lane holds A[m=c15][k=kb*32+q*8+i], i=0..7
//  B-frag: lane holds B[k=kb*32+q*8+i][n=cblk*16+c15]
//  C/D:    lane holds C[row=q*4+ii][col=c15]
// W packed (d_ws) B-frag order per matrix: idx = (((cblk*8+kb)*64+ln)*8+i)
//  (cblk = global 16-col block 0..15; here cblk = w*2+cb, w=0..7, cb=0..1)
// LDS state swizzle: elem(r,k) -> r*256 + (((k>>3)^r)&31)*8 + (k&7)

typedef __attribute__((ext_vector_type(8))) short bf16x8;
typedef __attribute__((ext_vector_type(4))) float f32x4;

#if __has_builtin(__builtin_amdgcn_exp2f)
#define EXP2F(x) __builtin_amdgcn_exp2f(x)
#else
#define EXP2F(x) __expf((x) * 0.6931471805599453f)
#endif

__device__ __forceinline__ short f2bf(float f) {
    unsigned u = __float_as_uint(f);
    unsigned r = (u + 0x7FFFu + ((u >> 16) & 1u)) >> 16;
    return (short)r;
}
__device__ __forceinline__ float bf2f(short h) {
    return __uint_as_float(((unsigned)(unsigned short)h) << 16);
}
// packed bf16 pair via HW convert (RNE, same rounding as f2bf)
__device__ __forceinline__ unsigned cvtpk(float lo, float hi) {
    unsigned r;
    asm("v_cvt_pk_bf16_f32 %0, %1, %2" : "=v"(r) : "v"(lo), "v"(hi));
    return r;
}
// rcp(1 + e^{2x}); tanh(x) = 1 - 2*this; 1 - tanh(x) = 2*this
__device__ __forceinline__ float rcp_1pe2x(float x) {
    float e = EXP2F(x * 2.8853900817779268f);   // 2*log2(e)
    return __builtin_amdgcn_rcpf(e + 1.0f);
}
__device__ __forceinline__ float fast_tanh(float x) {
    return fmaf(-2.0f, rcp_1pe2x(x), 1.0f);
}
__device__ __forceinline__ int sw_off(int r, int k) {
    return r * 256 + ((((k >> 3) ^ r) & 31) << 3) + (k & 7);
}
__device__ __forceinline__ unsigned pk2(float a, float b) { return cvtpk(a, b); }
__device__ __forceinline__ float upk(unsigned p, int hi) {
    return __uint_as_float(hi ? (p & 0xFFFF0000u) : (p << 16));
}

// ---------------- pack weights fp32 -> bf16, B-frag order (LDS transpose) ----------------
// grid: 96 blocks = mat(12) x kb(8), 256 threads.
// Slab = W[l][kb*32 .. kb*32+32)[0..256): 32x256 fp32, loaded coalesced
// (float4), transposed through LDS [n][k'] (stride 40 shorts: rows 16B-aligned,
// bank starts spread), stored as contiguous bf16x8 in B-frag order.
__global__ void pack_w(const float* __restrict__ Wz, const float* __restrict__ Wg,
                       const float* __restrict__ Wr, const float* __restrict__ Wh,
                       short* __restrict__ out) {
    __shared__ __align__(16) short lds[256 * 40];   // 20 KB
    int mat = blockIdx.x >> 3;       // 0..11 = l*4+g
    int kb  = blockIdx.x & 7;        // 0..7
    int l = mat >> 2, g = mat & 3;
    const float* W = (g == 0) ? Wz : (g == 1) ? Wg : (g == 2) ? Wr : Wh;
    const float* Wsl = W + l * 65536 + kb * 32 * 256;   // slab [32][256]
    const int t = threadIdx.x;

    // load: 2048 float4, coalesced; f -> k'=f>>6, n0=(f&63)*4
#pragma unroll
    for (int j = 0; j < 8; j++) {
        int f  = j * 256 + t;
        int kp = f >> 6;
        int n0 = (f & 63) * 4;
        float4 v = ((const float4*)Wsl)[f];
        lds[(n0 + 0) * 40 + kp] = f2bf(v.x);
        lds[(n0 + 1) * 40 + kp] = f2bf(v.y);
        lds[(n0 + 2) * 40 + kp] = f2bf(v.z);
        lds[(n0 + 3) * 40 + kp] = f2bf(v.w);
    }
    __syncthreads();

    // store: out[mat][(((c*8+kb)*64+ln)*8+i)] = W[kb*32+(ln>>4)*8+i][c*16+(ln&15)]
    short* outm = out + mat * 65536;
#pragma unroll
    for (int j = 0; j < 4; j++) {
        int vp = j * 256 + t;
        int c  = vp >> 6;
        int ln = vp & 63;
        int n   = c * 16 + (ln & 15);
        int kp0 = (ln >> 4) * 8;
        bf16x8 val = *(const bf16x8*)(lds + n * 40 + kp0);
        *(bf16x8*)(outm + (((c * 8 + kb) * 64 + ln) << 3)) = val;
    }
}

// ---------------- one gate GEMM: acc = bias + X@U + In@W ----------------
// wave tile: 32 rows x 32 cols -> acc[2][2]
__device__ __forceinline__ void gate_gemm(const short* __restrict__ In,   // LDS [32][256] swizzled
                                          const short* __restrict__ Wm,   // packed bf16 65536
                                          const float* __restrict__ U,    // [2][256] fp32
                                          const float* __restrict__ bias, // [256]
                                          const float2* __restrict__ txS, // LDS [32]
                                          int q, int c15, int w,
                                          f32x4 acc[2][2]) {
    float2 tx[8];
#pragma unroll
    for (int rb = 0; rb < 2; rb++)
#pragma unroll
        for (int ii = 0; ii < 4; ii++) tx[rb * 4 + ii] = txS[rb * 16 + q * 4 + ii];
#pragma unroll
    for (int cb = 0; cb < 2; cb++) {
        int col = (w * 2 + cb) * 16 + c15;
        float u0 = U[col], u1 = U[256 + col], bb = bias[col];
#pragma unroll
        for (int rb = 0; rb < 2; rb++)
#pragma unroll
            for (int ii = 0; ii < 4; ii++)
                acc[rb][cb][ii] = bb + tx[rb * 4 + ii].x * u0 + tx[rb * 4 + ii].y * u1;
    }
    __builtin_amdgcn_s_setprio(1);
#pragma unroll
    for (int kb = 0; kb < 8; kb++) {
        bf16x8 a[2];
#pragma unroll
        for (int rb = 0; rb < 2; rb++) {
            int r = rb * 16 + c15;
            a[rb] = *(const bf16x8*)(In + r * 256 + ((((kb * 4 + q) ^ r) & 31) << 3));
        }
#pragma unroll
        for (int cb = 0; cb < 2; cb++) {
            bf16x8 b = *(const bf16x8*)(Wm + ((((w * 2 + cb) * 8 + kb) * 64 + (q * 16 + c15)) << 3));
#pragma unroll
            for (int rb = 0; rb < 2; rb++)
                acc[rb][cb] = __builtin_amdgcn_mfma_f32_16x16x32_bf16(a[rb], b, acc[rb][cb], 0, 0, 0);
        }
    }
    __builtin_amdgcn_s_setprio(0);
}

// ---------------- main kernel: 32 rows/WG, 512 threads (8 waves) ----------------
__global__ __launch_bounds__(512, 4)
void dgm_main(const float* __restrict__ T, const float* __restrict__ X,
              const float* __restrict__ W0, const float* __restrict__ b0,
              const float* __restrict__ Uz, const float* __restrict__ Ug,
              const float* __restrict__ Ur, const float* __restrict__ Uh,
              const float* __restrict__ bz, const float* __restrict__ bg,
              const float* __restrict__ br, const float* __restrict__ bh,
              const float* __restrict__ Wf, const float* __restrict__ bfp,
              const short* __restrict__ Wp, float* __restrict__ out) {
    __shared__ __align__(16) short Sb[8192];    // 16 KB: S (holds S*R mid-layer)
    __shared__ __align__(16) short S1b[8192];   // 16 KB: S1, immutable
    __shared__ float2 txS[32];

    const int tid = threadIdx.x;
    const int w   = tid >> 6;        // 0..7
    const int ln  = tid & 63;
    const int q   = ln >> 4;
    const int c15 = ln & 15;
    const int m0  = blockIdx.x * 32;

    if (tid < 32) txS[tid] = make_float2(T[m0 + tid], X[m0 + tid]);
    __syncthreads();

    // ---- S1 = tanh(X@W0 + b0); S = S1. 512 thr: (col, half of rows) each ----
    {
        int col  = tid & 255;
        int half = tid >> 8;         // 0/1 -> rows [half*16, half*16+16)
        float w00 = W0[col], w01 = W0[256 + col], bb = b0[col];
#pragma unroll 4
        for (int rr = 0; rr < 16; rr++) {
            int r = half * 16 + rr;
            float2 tx = txS[r];
            short v = f2bf(fast_tanh(tx.x * w00 + tx.y * w01 + bb));
            int off = sw_off(r, col);
            S1b[off] = v;
            Sb[off]  = v;
        }
    }
    __syncthreads();

    // register mirror of this thread's owned S elements (C-layout), packed bf16
    unsigned sreg[2][2][2];
#pragma unroll
    for (int rb = 0; rb < 2; rb++)
#pragma unroll
        for (int cb = 0; cb < 2; cb++) {
            int col = (w * 2 + cb) * 16 + c15;
#pragma unroll
            for (int p = 0; p < 2; p++) {
                unsigned lo = (unsigned short)Sb[sw_off(rb * 16 + q * 4 + 2 * p,     col)];
                unsigned hi = (unsigned short)Sb[sw_off(rb * 16 + q * 4 + 2 * p + 1, col)];
                sreg[rb][cb][p] = lo | (hi << 16);
            }
        }

    // ---- layers ----
    for (int l = 0; l < 3; l++) {
        const short* Wzp = Wp + (l * 4 + 0) * 65536;
        const short* Wgp = Wp + (l * 4 + 1) * 65536;
        const short* Wrp = Wp + (l * 4 + 2) * 65536;
        const short* Whp = Wp + (l * 4 + 3) * 65536;

        f32x4 acc[2][2];
        unsigned zsp[2][2][2], srp[2][2][2], gmp[2][2][2];

        // Z gate: zs = tanh(Z)*S_old
        gate_gemm(Sb, Wzp, Uz + l * 512, bz + l * 256, txS, q, c15, w, acc);
#pragma unroll
        for (int rb = 0; rb < 2; rb++)
#pragma unroll
            for (int cb = 0; cb < 2; cb++)
#pragma unroll
                for (int p = 0; p < 2; p++)
                    zsp[rb][cb][p] = pk2(
                        fast_tanh(acc[rb][cb][2 * p])     * upk(sreg[rb][cb][p], 0),
                        fast_tanh(acc[rb][cb][2 * p + 1]) * upk(sreg[rb][cb][p], 1));

        // R gate: sr = S_old*tanh(R)
        gate_gemm(Sb, Wrp, Ur + l * 512, br + l * 256, txS, q, c15, w, acc);
#pragma unroll
        for (int rb = 0; rb < 2; rb++)
#pragma unroll
            for (int cb = 0; cb < 2; cb++)
#pragma unroll
                for (int p = 0; p < 2; p++)
                    srp[rb][cb][p] = pk2(
                        upk(sreg[rb][cb][p], 0) * fast_tanh(acc[rb][cb][2 * p]),
                        upk(sreg[rb][cb][p], 1) * fast_tanh(acc[rb][cb][2 * p + 1]));

        // G gate (reads only S1b): 1 - tanh(G) = 2*rcp(e^{2G}+1)
        gate_gemm(S1b, Wgp, Ug + l * 512, bg + l * 256, txS, q, c15, w, acc);
#pragma unroll
        for (int rb = 0; rb < 2; rb++)
#pragma unroll
            for (int cb = 0; cb < 2; cb++)
#pragma unroll
                for (int p = 0; p < 2; p++)
                    gmp[rb][cb][p] = pk2(2.0f * rcp_1pe2x(acc[rb][cb][2 * p]),
                                         2.0f * rcp_1pe2x(acc[rb][cb][2 * p + 1]));

        __syncthreads();   // B1: all Sb reads (Z,R A-frags) done
#pragma unroll
        for (int rb = 0; rb < 2; rb++)
#pragma unroll
            for (int cb = 0; cb < 2; cb++) {
                int col = (w * 2 + cb) * 16 + c15;
#pragma unroll
                for (int p = 0; p < 2; p++) {
                    Sb[sw_off(rb * 16 + q * 4 + 2 * p,     col)] = (short)(srp[rb][cb][p] & 0xFFFFu);
                    Sb[sw_off(rb * 16 + q * 4 + 2 * p + 1, col)] = (short)(srp[rb][cb][p] >> 16);
                }
            }
        __syncthreads();   // B2: Sb = S*R visible

        // H gate (reads Sb = S*R)
        gate_gemm(Sb, Whp, Uh + l * 512, bh + l * 256, txS, q, c15, w, acc);

        // S_new = (1-G)*tanh(H) + zs  (no Sb access here)
#pragma unroll
        for (int rb = 0; rb < 2; rb++)
#pragma unroll
            for (int cb = 0; cb < 2; cb++)
#pragma unroll
                for (int p = 0; p < 2; p++) {
                    float sn0 = fmaf(upk(gmp[rb][cb][p], 0),
                                     fast_tanh(acc[rb][cb][2 * p]),
                                     upk(zsp[rb][cb][p], 0));
                    float sn1 = fmaf(upk(gmp[rb][cb][p], 1),
                                     fast_tanh(acc[rb][cb][2 * p + 1]),
                                     upk(zsp[rb][cb][p], 1));
                    srp[rb][cb][p] = pk2(sn0, sn1);
                }

        __syncthreads();   // B3: all H A-frag reads of Sb done
#pragma unroll
        for (int rb = 0; rb < 2; rb++)
#pragma unroll
            for (int cb = 0; cb < 2; cb++) {
                int col = (w * 2 + cb) * 16 + c15;
#pragma unroll
                for (int p = 0; p < 2; p++) {
                    Sb[sw_off(rb * 16 + q * 4 + 2 * p,     col)] = (short)(srp[rb][cb][p] & 0xFFFFu);
                    Sb[sw_off(rb * 16 + q * 4 + 2 * p + 1, col)] = (short)(srp[rb][cb][p] >> 16);
                    sreg[rb][cb][p] = srp[rb][cb][p];
                }
            }
        __syncthreads();   // B4: new S visible
    }

    // ---- out = S @ Wf + bf : 16 threads/row, vectorized LDS reads ----
    {
        int row = tid >> 4;          // 0..31
        int seg = tid & 15;          // 16 threads per row
        float sum = 0.0f;
#pragma unroll
        for (int j = 0; j < 2; j++) {
            int ch = seg * 2 + j;    // 0..31 (8-elem chunks)
            bf16x8 sv = *(const bf16x8*)(Sb + row * 256 + (((ch ^ row) & 31) << 3));
            float4 wa = *(const float4*)(Wf + ch * 8);
            float4 wb = *(const float4*)(Wf + ch * 8 + 4);
            sum += bf2f(sv[0]) * wa.x + bf2f(sv[1]) * wa.y + bf2f(sv[2]) * wa.z + bf2f(sv[3]) * wa.w
                 + bf2f(sv[4]) * wb.x + bf2f(sv[5]) * wb.y + bf2f(sv[6]) * wb.z + bf2f(sv[7]) * wb.w;
        }
        sum += __shfl_down(sum, 8, 16);
        sum += __shfl_down(sum, 4, 16);
        sum += __shfl_down(sum, 2, 16);
        sum += __shfl_down(sum, 1, 16);
        if (seg == 0) out[m0 + row] = sum + bfp[0];
    }
}

extern "C" void kernel_launch(void* const* d_in, const int* in_sizes, int n_in,
                              void* d_out, int out_size, void* d_ws, size_t ws_size,
                              hipStream_t stream) {
    const float* T  = (const float*)d_in[0];
    const float* X  = (const float*)d_in[1];
    const float* W0 = (const float*)d_in[2];
    const float* b0 = (const float*)d_in[3];
    const float* Uz = (const float*)d_in[4];
    const float* Ug = (const float*)d_in[5];
    const float* Ur = (const float*)d_in[6];
    const float* Uh = (const float*)d_in[7];
    const float* Wz = (const float*)d_in[8];
    const float* Wg = (const float*)d_in[9];
    const float* Wr = (const float*)d_in[10];
    const float* Wh = (const float*)d_in[11];
    const float* bz = (const float*)d_in[12];
    const float* bg = (const float*)d_in[13];
    const float* br = (const float*)d_in[14];
    const float* bh = (const float*)d_in[15];
    const float* Wf = (const float*)d_in[16];
    const float* bfp= (const float*)d_in[17];
    float* out = (float*)d_out;
    short* Wp = (short*)d_ws;           // 12*65536 bf16 = 1.5 MB
    const int N = in_sizes[0];

    pack_w<<<96, 256, 0, stream>>>(Wz, Wg, Wr, Wh, Wp);
    dgm_main<<<N / 32, 512, 0, stream>>>(T, X, W0, b0, Uz, Ug, Ur, Uh,
                                         bz, bg, br, bh, Wf, bfp, Wp, out);
}